// Round 12
// baseline (1012.922 us; speedup 1.0000x reference)
//
#include <hip/hip_runtime.h>
#include <math.h>

#define CDIM 32
#define HWDIM 2304            // 48*48
#define BDIM 16
#define PPW 8                 // pixels per wave (8 lanes per pixel)
#define NTHREADS 256          // 4 waves => 32 pixels per block
#define PPB 32
#define ZOFF (BDIM * CDIM * HWDIM)   // z elements, then 16 logdet floats

// R10/R11 lessons: time tracks TOTAL dynamic instructions at ~25% issue
// efficiency regardless of wave count (R10: same per-wave count, 2x waves,
// 2x time, VALUBusy flat) and the batch loop spills (R11). R12: cut the
// instruction count on the proven skeleton (R3 staging + R3 right-looking
// algebra + R7 DPP bcast8, (256,2), single batch) via v_pk_fma_f32:
// A stored as f32x2 A2[4][16]; trailing update = one packed FMA per
// (q, column-pair); multipliers pre-negated per k so updates are pure
// fma(mn,u,a). k even -> one scalar .y head at j=k+1 (pivot's own pair);
// pairs from jh=(k>>1)+1 for all k. ~3400 -> ~2450 solver ops.
typedef __attribute__((ext_vector_type(2))) float f32x2;

__device__ __forceinline__ void gload_lds16(const float* g, float* l) {
    __builtin_amdgcn_global_load_lds(
        (const __attribute__((address_space(1))) float*)g,
        (__attribute__((address_space(3))) float*)l, 16, 0, 0);
}

// Broadcast lane (group_base + k7) to all 8 lanes of each aligned 8-lane
// group (R7-proven DPP pair; k7 compile-time, call sites fully unrolled).
__device__ __forceinline__ float bcast8(float x, int k7) {
    int v = __float_as_int(x), b;
    switch (k7) {
    case 0: b = __builtin_amdgcn_update_dpp(v, v, 0x00, 0xF, 0xF, false);
            b = __builtin_amdgcn_update_dpp(b, b, 0x114, 0xF, 0xA, false); break;
    case 1: b = __builtin_amdgcn_update_dpp(v, v, 0x55, 0xF, 0xF, false);
            b = __builtin_amdgcn_update_dpp(b, b, 0x114, 0xF, 0xA, false); break;
    case 2: b = __builtin_amdgcn_update_dpp(v, v, 0xAA, 0xF, 0xF, false);
            b = __builtin_amdgcn_update_dpp(b, b, 0x114, 0xF, 0xA, false); break;
    case 3: b = __builtin_amdgcn_update_dpp(v, v, 0xFF, 0xF, 0xF, false);
            b = __builtin_amdgcn_update_dpp(b, b, 0x114, 0xF, 0xA, false); break;
    case 4: b = __builtin_amdgcn_update_dpp(v, v, 0x00, 0xF, 0xF, false);
            b = __builtin_amdgcn_update_dpp(b, b, 0x104, 0xF, 0x5, false); break;
    case 5: b = __builtin_amdgcn_update_dpp(v, v, 0x55, 0xF, 0xF, false);
            b = __builtin_amdgcn_update_dpp(b, b, 0x104, 0xF, 0x5, false); break;
    case 6: b = __builtin_amdgcn_update_dpp(v, v, 0xAA, 0xF, 0xF, false);
            b = __builtin_amdgcn_update_dpp(b, b, 0x104, 0xF, 0x5, false); break;
    default: b = __builtin_amdgcn_update_dpp(v, v, 0xFF, 0xF, 0xF, false);
            b = __builtin_amdgcn_update_dpp(b, b, 0x104, 0xF, 0x5, false); break;
    }
    return __int_as_float(b);
}

// packed 2xFP32 FMA: acc = ab*u + acc (VOP3P, 2 FLOPs/lane/instr)
__device__ __forceinline__ f32x2 pkfma(f32x2 ab, f32x2 u, f32x2 acc) {
    asm("v_pk_fma_f32 %0, %1, %2, %0" : "+v"(acc) : "v"(ab), "v"(u));
    return acc;
}

__global__ __launch_bounds__(NTHREADS, 2)
void solve_kernel(const float* __restrict__ input,
                  const float* __restrict__ weight,
                  const float* __restrict__ logdet,
                  float* __restrict__ out) {
    const int t    = threadIdx.x;
    const int lane = t & 63;
    const int wv   = t >> 6;           // wave 0..3
    const int h    = lane & 7;         // row class: owns rows i = 8r + h
    const int p    = lane >> 3;        // pixel-in-wave 0..7

    const int blk  = blockIdx.x;
    const int b    = blk / (HWDIM / PPB);       // 72 blocks per batch image
    const int pb   = (blk % (HWDIM / PPB)) * PPB;  // block pixel base
    const int pixl = wv * PPW + p;              // pixel-in-block 0..31
    const int pix0 = pb + wv * PPW;             // wave pixel base (logdet cond)
    const int pix  = pb + pixl;

    __shared__ float lds[2][256 * CDIM];        // 2 x 32KB chunk ring

    // ---- x: scalar loads, issued first (oldest in vmcnt order) ----
    const float* xp = input + (size_t)b * CDIM * HWDIM + (size_t)h * HWDIM + pix;
    float y[4];
    #pragma unroll
    for (int r = 0; r < 4; ++r) y[r] = xp[(size_t)(r * 8) * HWDIM];
    asm volatile("" ::: "memory");     // pin: x loads oldest in vmcnt order

    // ---- DMA staging (R3-verbatim): chunk r = rc-rows [256r, 256r+256) ----
    const int sg = lane >> 3;
    const int sp = lane & 7;
    const int ps = pixl >> 2, pc = pixl & 3;
    const float* wbase = weight + (size_t)b * (CDIM * CDIM) * HWDIM + pb;
    const float* srcA = wbase + (size_t)(wv * 64 + sg) * HWDIM
                              + ((sp ^ (2 * wv)) << 2);
    const float* srcB = wbase + (size_t)(wv * 64 + sg) * HWDIM
                              + ((sp ^ (2 * wv + 1)) << 2);

    auto stage = [&](int r, int buf) {
        float* lbase = &lds[buf][(wv * 64) * CDIM];
        #pragma unroll
        for (int q = 0; q < 8; ++q) {
            const float* s = (q < 4 ? srcA : srcB)
                           + (size_t)(r * 256 + q * 8) * HWDIM;
            gload_lds16(s, lbase + q * 8 * CDIM);
        }
    };

    stage(0, 0);
    asm volatile("" ::: "memory");
    stage(1, 1);

    // A[q][j] lives in A2[q][j>>1] (.x = even j, .y = odd j)
    f32x2 A2[4][16];
    #pragma unroll
    for (int r = 0; r < 4; ++r) {
        if (r < 3) asm volatile("s_waitcnt vmcnt(8)" ::: "memory");
        else       asm volatile("s_waitcnt vmcnt(0)" ::: "memory");
        __builtin_amdgcn_s_barrier();
        asm volatile("" ::: "memory");
        const int slot = ((ps ^ h) << 2) + pc;
        #pragma unroll
        for (int jh = 0; jh < 16; ++jh) {
            f32x2 v;
            v.x = lds[r & 1][(h * CDIM + 2 * jh) * CDIM + slot];
            v.y = lds[r & 1][(h * CDIM + 2 * jh + 1) * CDIM + slot];
            A2[r][jh] = v;
        }
        if (r < 2) {
            asm volatile("s_waitcnt lgkmcnt(0)" ::: "memory");
            __builtin_amdgcn_s_barrier();
            asm volatile("" ::: "memory");
            stage(r + 2, r & 1);
        }
    }

    // ---- right-looking LU, no pivoting (R3-verbatim algebra; owner row
    // scaled to unit diagonal via m_owner = 1-r, all multipliers negated) --
    float lacc = 0.0f;
    #pragma unroll
    for (int k = 0; k < CDIM; ++k) {
        const int tr = k >> 3, k7 = k & 7;
        const float akk = (k & 1) ? A2[tr][k >> 1].y : A2[tr][k >> 1].x;
        float bp = bcast8(akk, k7);
        float rc = __builtin_amdgcn_rcpf(bp);
        lacc += __log2f(fabsf(bp));
        const float rn = -rc;

        float mn[4];   // negated multipliers: update is a += mn*bv
        mn[tr] = (h > k7) ? akk * rn : ((h == k7) ? (rc - 1.0f) : 0.0f);
        #pragma unroll
        for (int q = tr + 1; q < 4; ++q) {
            const float aqk = (k & 1) ? A2[q][k >> 1].y : A2[q][k >> 1].x;
            mn[q] = aqk * rn;
        }

        // fused y elimination
        {
            float bq = bcast8(y[tr], k7);
            #pragma unroll
            for (int q = tr; q < 4; ++q) y[q] = fmaf(mn[q], bq, y[q]);
        }

        // scalar head (k even): j = k+1 is the .y of the pivot's own pair
        if ((k & 1) == 0) {
            const int jh = k >> 1;
            float bv = bcast8(A2[tr][jh].y, k7);
            #pragma unroll
            for (int q = tr; q < 4; ++q)
                A2[q][jh].y = fmaf(mn[q], bv, A2[q][jh].y);
        }

        // packed pairs: jh0 = (k>>1)+1 covers both parities exactly
        f32x2 m2[4];
        #pragma unroll
        for (int q = tr; q < 4; ++q) { f32x2 t; t.x = mn[q]; t.y = mn[q]; m2[q] = t; }
        #pragma unroll
        for (int jh = (k >> 1) + 1; jh < 16; ++jh) {
            f32x2 u2;
            u2.x = bcast8(A2[tr][jh].x, k7);
            u2.y = bcast8(A2[tr][jh].y, k7);
            #pragma unroll
            for (int q = tr; q < 4; ++q)
                A2[q][jh] = pkfma(m2[q], u2, A2[q][jh]);
        }
    }

    // ---- back-substitution (unit-diagonal U after owner scaling) ----
    #pragma unroll
    for (int k = CDIM - 1; k >= 1; --k) {
        const int tr = k >> 3, k7 = k & 7;
        float bz = bcast8(y[tr], k7);      // z[k] (rows finalize high->low)
        const float atk = (k & 1) ? A2[tr][k >> 1].y : A2[tr][k >> 1].x;
        float cm = (h < k7) ? atk : 0.0f;  // owner & done rows: no-op
        y[tr] = fmaf(-cm, bz, y[tr]);
        #pragma unroll
        for (int q = 0; q < tr; ++q) {
            const float aqk = (k & 1) ? A2[q][k >> 1].y : A2[q][k >> 1].x;
            y[q] = fmaf(-aqk, bz, y[q]);
        }
    }
    // y[r] = z[8r + h]

    // ---- store z (dense 32B-segment pattern) ----
    float* zp = out + (size_t)b * CDIM * HWDIM + (size_t)h * HWDIM + pix;
    #pragma unroll
    for (int r = 0; r < 4; ++r) zp[(size_t)(r * 8) * HWDIM] = y[r];

    // ---- logdet: lacc identical across a pixel's 8 lanes; 3 xor-shuffles
    // sum the wave's 8 pixel-groups; one atomic per wave. ----
    float v2 = lacc;
    v2 += __shfl_xor(v2, 8);
    v2 += __shfl_xor(v2, 16);
    v2 += __shfl_xor(v2, 32);
    if (lane == 0) {
        float add = -v2 * 0.69314718055994531f;  // ln2 * sum(log2|piv|)
        if (pix0 == 0) add += logdet[b];         // exactly one wave per b
        atomicAdd(&out[ZOFF + b], add);
    }
}

extern "C" void kernel_launch(void* const* d_in, const int* in_sizes, int n_in,
                              void* d_out, int out_size, void* d_ws, size_t ws_size,
                              hipStream_t stream) {
    const float* input  = (const float*)d_in[0];
    const float* weight = (const float*)d_in[1];
    const float* logdet = (const float*)d_in[2];
    float* out = (float*)d_out;

    solve_kernel<<<BDIM * (HWDIM / PPB), NTHREADS, 0, stream>>>(input, weight,
                                                                logdet, out);
}